// Round 2
// baseline (511.515 us; speedup 1.0000x reference)
//
#include <hip/hip_runtime.h>

// DiffAttnLayer: B=2,N=2048,EMB=1024,H=8,HD=64,FF=4096.
// Inputs fp32 (runtime-detected); output dtype follows input dtype.
// R10 = R9 + attn latency-bound fixes:
//  - q-tile 64->32 rows, grid 1024, LDS 40KB -> 4 blocks/CU (was 2)
//  - defer-max (THR=8): skip rescale chain on non-growing tiles
//  - P-pack dual ds_write_b32 (asm) with quad-selected dword slot: kills the
//    4-way bank conflict of the b64 pack write (R9: 4.125 conflicts/write)
//  - bijective XCD remap so each XCD keeps 2 (b,h) K/V sets L2-resident
// Workspace: 5 x 8MB slots + scalars @40MB:
//  A: h1 -> ob -> h2        B: q -> g(lo)      C: k -> g(hi)
//  D: vT -> WoT -> W1Th|W2Th                   E: WqT|WkT|WvT -> x2

typedef unsigned short u16;
typedef unsigned int u32;
typedef __attribute__((ext_vector_type(8))) __bf16 bf16x8;
typedef __attribute__((ext_vector_type(4))) float f32x4;
typedef __attribute__((ext_vector_type(4))) u32 u32x4;
typedef __attribute__((ext_vector_type(2))) u32 u32x2;

#define LOG2E 1.4426950408889634f
#define LAM_INIT 0.355509068f
#define ONE_MINUS_LAM_INIT 0.644490932f

__device__ __forceinline__ float bf2f(u16 x) {
  u32 u = ((u32)x) << 16;
  return __builtin_bit_cast(float, u);
}
__device__ __forceinline__ u16 f2bf(float f) {
  u32 u = __builtin_bit_cast(u32, f);
  u32 r = (u + 0x7FFFu + ((u >> 16) & 1u)) >> 16;
  return (u16)r;
}
__device__ __forceinline__ u32 cvtpk(float lo, float hi) {
  u32 r;
  asm("v_cvt_pk_bf16_f32 %0, %1, %2" : "=v"(r) : "v"(lo), "v"(hi));
  return r;
}
__device__ __forceinline__ float ldf(const void* p, size_t i, bool f32) {
  return f32 ? ((const float*)p)[i] : bf2f(((const u16*)p)[i]);
}
// global -> LDS async DMA, 16B/lane; LDS dest = wave-uniform base + lane*16.
__device__ __forceinline__ void async16(const u16* g, u16* l) {
  __builtin_amdgcn_global_load_lds((const __attribute__((address_space(1))) u32*)g,
                                   (__attribute__((address_space(3))) u32*)l, 16, 0, 0);
}
__device__ __forceinline__ bf16x8 ld8(const u16* p) { return *(const bf16x8*)p; }
// un-fusable b32 LDS store (keeps dword-phase bank layout under our control)
__device__ __forceinline__ void ds_write32(u16* l, u32 v) {
  asm volatile("ds_write_b32 %0, %1" ::"v"(
                   (u32)(size_t)(__attribute__((address_space(3))) void*)l),
               "v"(v)
               : "memory");
}

// ---------------- input-dtype detector (1 = bf16, 0 = fp32) ----------------
__global__ void detect_kernel(const u32* x, int* flag) {
  int e = (x[threadIdx.x] >> 7) & 0xFF;
  unsigned long long m = __ballot(e >= 90 && e <= 150);
  if (threadIdx.x == 0) flag[0] = (__popcll(m) >= 40) ? 1 : 0;
}

// ---------------- lambda ----------------
__global__ void lam_kernel(const void* lq1, const void* lk1, const void* lq2,
                           const void* lk2, const int* flag, float* out) {
  const bool f32 = flag[0] == 0;
  int L = threadIdx.x;
  float a = ldf(lq1, L, f32) * ldf(lk1, L, f32);
  float c = ldf(lq2, L, f32) * ldf(lk2, L, f32);
#pragma unroll
  for (int m = 1; m < 64; m <<= 1) { a += __shfl_xor(a, m); c += __shfl_xor(c, m); }
  if (L == 0) out[0] = __expf(a) - __expf(c) + LAM_INIT;
}

// ---------------- LayerNorm over 1024, one wave per row ----------------
__device__ __forceinline__ void unpack8(u32x4 u, float* f) {
#pragma unroll
  for (int i = 0; i < 4; ++i) {
    f[2 * i] = bf2f((u16)(u[i] & 0xffffu));
    f[2 * i + 1] = bf2f((u16)(u[i] >> 16));
  }
}

template <bool XRAW>
__global__ __launch_bounds__(256) void ln_kernel(const void* __restrict__ x,
                                                 const void* __restrict__ w,
                                                 const void* __restrict__ b,
                                                 const int* __restrict__ flag,
                                                 u16* __restrict__ out) {
  const bool f32 = flag[0] == 0;
  const int row = blockIdx.x * 4 + (threadIdx.x >> 6);
  const int L = threadIdx.x & 63;
  float xv[16];
  if (XRAW && f32) {
    const f32x4* xr = (const f32x4*)((const float*)x + (size_t)row * 1024 + L * 16);
#pragma unroll
    for (int i = 0; i < 4; ++i) {
      f32x4 vv = xr[i];
#pragma unroll
      for (int j = 0; j < 4; ++j) xv[i * 4 + j] = vv[j];
    }
  } else {
    const u16* xr = (const u16*)x + (size_t)row * 1024 + L * 16;
    unpack8(*(const u32x4*)xr, xv);
    unpack8(*(const u32x4*)(xr + 8), xv + 8);
  }
  float s = 0.f, sq = 0.f;
#pragma unroll
  for (int i = 0; i < 16; ++i) { s += xv[i]; sq += xv[i] * xv[i]; }
#pragma unroll
  for (int m = 1; m < 64; m <<= 1) { s += __shfl_xor(s, m); sq += __shfl_xor(sq, m); }
  float mean = s * (1.0f / 1024.0f);
  float var = sq * (1.0f / 1024.0f) - mean * mean;
  float rstd = rsqrtf(var + 1e-5f);
  u32 pk[8];
#pragma unroll
  for (int i = 0; i < 8; ++i) {
    float w0 = ldf(w, L * 16 + 2 * i, f32), w1 = ldf(w, L * 16 + 2 * i + 1, f32);
    float b0 = ldf(b, L * 16 + 2 * i, f32), b1v = ldf(b, L * 16 + 2 * i + 1, f32);
    float v0 = (xv[2 * i] - mean) * rstd * w0 + b0;
    float v1 = (xv[2 * i + 1] - mean) * rstd * w1 + b1v;
    pk[i] = (u32)f2bf(v0) | ((u32)f2bf(v1) << 16);
  }
  u32x4 o0 = {pk[0], pk[1], pk[2], pk[3]};
  u32x4 o1 = {pk[4], pk[5], pk[6], pk[7]};
  *(u32x4*)(out + (size_t)row * 1024 + L * 16) = o0;
  *(u32x4*)(out + (size_t)row * 1024 + L * 16 + 8) = o1;
}

// -------- transpose+convert: dst[z][c][r] = (bf16)src_z[r][c], z-multiplexed --------
__global__ __launch_bounds__(256) void twc_kernel(const void* __restrict__ s0,
                                                  const void* __restrict__ s1,
                                                  const void* __restrict__ s2,
                                                  u16* __restrict__ dst, int sstride,
                                                  int dstride, size_t soff, size_t dzoff,
                                                  const int* __restrict__ flag) {
  __shared__ __align__(16) u16 tile[64][72];
  const bool f32 = flag[0] == 0;
  const void* src = blockIdx.z == 0 ? s0 : (blockIdx.z == 1 ? s1 : s2);
  u16* dz = dst + (size_t)blockIdx.z * dzoff;
  const int r0 = blockIdx.y * 64, c0 = blockIdx.x * 64;
  const int t = threadIdx.x;
  const int rr = t >> 3, cc = t & 7;
#pragma unroll
  for (int i = 0; i < 2; ++i) {
    int row = rr + i * 32;
    size_t idx = (size_t)(r0 + row) * sstride + c0 + cc * 8 + soff;
    if (f32) {
      const f32x4* s = (const f32x4*)((const float*)src + idx);
      f32x4 a = s[0], b = s[1];
      union { u16 t16[8]; u32x4 v; } u_;
#pragma unroll
      for (int j = 0; j < 4; ++j) { u_.t16[j] = f2bf(a[j]); u_.t16[4 + j] = f2bf(b[j]); }
      *(u32x4*)(&tile[row][cc * 8]) = u_.v;
    } else {
      *(u32x4*)(&tile[row][cc * 8]) = *(const u32x4*)((const u16*)src + idx);
    }
  }
  __syncthreads();
  u16* d = dz + (size_t)c0 * dstride + r0;
#pragma unroll
  for (int i = 0; i < 2; ++i) {
    int n = rr + i * 32;
    union { u16 t16[8]; u32x4 v; } u_;
#pragma unroll
    for (int j = 0; j < 8; ++j) u_.t16[j] = tile[cc * 8 + j][n];
    *(u32x4*)(d + (size_t)n * dstride + cc * 8) = u_.v;
  }
}

// ------------- GEMM: C(MxN) = A(MxK) * Bt(NxK)^T, tile TM x 128 --------------
enum { EP_NONE = 0, EP_RES = 2, EP_GELU = 3, EP_BIASRES = 4, EP_QKV = 5 };

template <int TM, int EPI, bool RESRAW, bool OUTFLEX>
__global__ __launch_bounds__(256, 2) void gemm_bt(
    const u16* __restrict__ A, const u16* __restrict__ Bt, void* __restrict__ Cv,
    int M, int N, int K, const void* __restrict__ bias, int boff,
    const void* __restrict__ res, const int* __restrict__ flag,
    u16* __restrict__ kout, u16* __restrict__ vtout) {
  constexpr int MT = TM / 32;  // acc tiles per wave in M
  __shared__ __align__(16) u16 lds[TM * 64 + 128 * 64];
  const int t = threadIdx.x;
  const int w = t >> 6, L = t & 63;
  const int quad = L >> 4, l16 = L & 15;
  const int m0 = blockIdx.y * TM, n0 = blockIdx.x * 128;
  const int wm = (TM == 128) ? (w >> 1) * 64 : (w & 1) * 32;
  const int wn = (TM == 128) ? (w & 1) * 64 : (w >> 1) * 64;
  const int srow = L >> 3, spc = L & 7;
  const int sc = spc ^ srow;
  constexpr int BBASE = TM * 64;

  f32x4 acc[MT][4] = {};
  const u16* Ab = A + (size_t)m0 * K;
  const u16* Bb = Bt + (size_t)n0 * K;

  for (int kt = 0; kt < K; kt += 64) {
#pragma unroll
    for (int r = 0; r < TM / 32; ++r) {
      int row = r * 32 + w * 8 + srow;
      async16(Ab + (size_t)row * K + kt + sc * 8, &lds[row * 64 + spc * 8]);
    }
#pragma unroll
    for (int r = 0; r < 4; ++r) {
      int row = r * 32 + w * 8 + srow;
      async16(Bb + (size_t)row * K + kt + sc * 8, &lds[BBASE + row * 64 + spc * 8]);
    }
    __syncthreads();
#pragma unroll
    for (int ks = 0; ks < 2; ++ks) {
      bf16x8 af[MT], bfr[4];
#pragma unroll
      for (int mt = 0; mt < MT; ++mt) {
        int row = wm + mt * 16 + l16;
        af[mt] = ld8(&lds[row * 64 + (((ks * 4 + quad) ^ (l16 & 7)) * 8)]);
      }
#pragma unroll
      for (int nt = 0; nt < 4; ++nt) {
        int row = wn + nt * 16 + l16;
        bfr[nt] = ld8(&lds[BBASE + row * 64 + (((ks * 4 + quad) ^ (l16 & 7)) * 8)]);
      }
#pragma unroll
      for (int mt = 0; mt < MT; ++mt)
#pragma unroll
        for (int nt = 0; nt < 4; ++nt)
          acc[mt][nt] =
              __builtin_amdgcn_mfma_f32_16x16x32_bf16(af[mt], bfr[nt], acc[mt][nt], 0, 0, 0);
    }
    __syncthreads();
  }

  const bool f32 = flag[0] == 0;
#pragma unroll
  for (int mt = 0; mt < MT; ++mt) {
#pragma unroll
    for (int nt = 0; nt < 4; ++nt) {
      int col = n0 + wn + nt * 16 + l16;
      float bv = 0.f;
      if (EPI == EP_GELU || EPI == EP_BIASRES) bv = ldf(bias, (size_t)boff + col, f32);
#pragma unroll
      for (int r = 0; r < 4; ++r) {
        int row = m0 + wm + mt * 16 + quad * 4 + r;
        float v = acc[mt][nt][r];
        if (EPI == EP_GELU) {
          v += bv;
          v = 0.5f * v * (1.0f + erff(v * 0.70710678118654752f));
        }
        if (EPI == EP_RES || EPI == EP_BIASRES) {
          size_t ri = (size_t)row * N + col;
          float rv = RESRAW ? ldf(res, ri, f32) : bf2f(((const u16*)res)[ri]);
          v += rv;
          if (EPI == EP_BIASRES) v += bv;
        }
        if (EPI == EP_QKV) {
          if (col < 1024) {
            ((u16*)Cv)[(size_t)row * 1024 + col] = f2bf(v * 0.125f);  // q, pre-scaled
          } else if (col < 2048) {
            kout[(size_t)row * 1024 + (col - 1024)] = f2bf(v);  // k
          } else {  // v stored transposed: vT[(b*8+h)*128+d][2048]
            int c2 = col - 2048;
            int bb = row >> 11, n = row & 2047, hh = c2 >> 7, d = c2 & 127;
            vtout[(size_t)((bb * 8 + hh) * 128 + d) * 2048 + n] = f2bf(v);
          }
        } else {
          size_t ci = (size_t)row * N + col;
          if (OUTFLEX && f32)
            ((float*)Cv)[ci] = v;
          else
            ((u16*)Cv)[ci] = f2bf(v);
        }
      }
    }
  }
}

// ---------------- Flash differential attention (32-row q-tiles, 4 blk/CU) ----------
// grid 1024 = b(2) x h(8) x qtile(64 of 32 rows), XCD-remapped. 4 waves:
// comp=w>>1, rh=(w&1)*16 (16 q-rows per wave).
// LDS (u16): K[2][64][64] @0 | Vt[128][64] @8192 | P/Qstage[4][16][64] @16384 (40KB)
// S^T = mfma(K,Q): lane owns qrow rh+l16. O^T = mfma(vT,P^T).
// Defer-max: skip rescale unless row-max grows by >8 (tile 0 always rescales).
// P-pack: two asm ds_write_b32 with dword slot selected by quad>>1 -> 2 lanes/bank.
// 2 barriers/tile: stageK overlaps PV, stageV overlaps QK+softmax.
__global__ __launch_bounds__(256, 4) void attn_kernel(
    const u16* __restrict__ q, const u16* __restrict__ k, const u16* __restrict__ vT,
    const float* __restrict__ lamp, const void* __restrict__ subw,
    const int* __restrict__ flag, u16* __restrict__ o) {
  __shared__ __align__(16) u16 lds[20480];
  const int t = threadIdx.x, w = t >> 6, L = t & 63;
  const int quad = L >> 4, l16 = L & 15;
  // bijective XCD remap (1024 = 8 x 128): XCD x keeps (b,h) pairs {2x,2x+1}
  const int bid = ((blockIdx.x & 7) << 7) | (blockIdx.x >> 3);
  const int qt = bid & 63, h = (bid >> 6) & 7, b = bid >> 9;
  const int q0 = qt * 32;
  const int comp = w >> 1, rh = (w & 1) * 16;
  const int srow = L >> 3, spc = L & 7, sc = spc ^ srow;
  const u16* vb = vT + (size_t)(b * 8 + h) * (128 * 2048);
  const int pbase = 16384 + w * 1024;

  auto stageK = [&](int kt) {
#pragma unroll
    for (int r = 0; r < 4; ++r) {
      int row = r * 32 + w * 8 + srow;  // comp=row>>6, key=row&63
      int c_ = row >> 6, key = row & 63;
      async16(k + ((size_t)(b * 2048 + kt + key) * 1024 + (2 * h + c_) * 64 + sc * 8),
              &lds[row * 64 + spc * 8]);
    }
  };
  auto stageV = [&](int kt) {
#pragma unroll
    for (int r = 0; r < 4; ++r) {
      int dim = r * 32 + w * 8 + srow;  // 0..127
      async16(vb + (size_t)dim * 2048 + kt + sc * 8, &lds[8192 + dim * 64 + spc * 8]);
    }
  };

  stageK(0);
  stageV(0);
  // stage Q (both comps, 32 rows each) into P region
#pragma unroll
  for (int r = 0; r < 2; ++r) {
    int row = r * 32 + w * 8 + srow;  // 0..63 : comp=row>>5, qrow=row&31
    int c_ = row >> 5, qr = row & 31;
    async16(q + ((size_t)(b * 2048 + q0 + qr) * 1024 + (2 * h + c_) * 64 + sc * 8),
            &lds[16384 + row * 64 + spc * 8]);
  }
  __syncthreads();  // all initial DMA (K0, V0, Q) drained
  bf16x8 qf[2];
#pragma unroll
  for (int ks = 0; ks < 2; ++ks)
    qf[ks] = ld8(&lds[16384 + comp * 2048 + (rh + l16) * 64 +
                      (((ks * 4 + quad) ^ (l16 & 7)) * 8)]);
  // no barrier: each wave's qf rows == its own (later) P rows; in-wave DS order

  float mst = -3.0e38f, lst = 0.f;
  f32x4 oacc[8] = {};

  for (int ti = 0; ti < 32; ++ti) {
    // S^T = Ktile * Q^T for own comp; lane owns qrow = rh + l16
    f32x4 s[4] = {};
#pragma unroll
    for (int ks = 0; ks < 2; ++ks) {
      bf16x8 kf[4];
#pragma unroll
      for (int nt = 0; nt < 4; ++nt) {
        int row = nt * 16 + l16;
        kf[nt] = ld8(&lds[comp * 4096 + row * 64 + (((ks * 4 + quad) ^ (l16 & 7)) * 8)]);
      }
#pragma unroll
      for (int nt = 0; nt < 4; ++nt)
        s[nt] = __builtin_amdgcn_mfma_f32_16x16x32_bf16(kf[nt], qf[ks], s[nt], 0, 0, 0);
    }

    // online softmax with defer-max (THR=8): per-lane row, 2 shfl per reduce
    float mx = -3.0e38f;
#pragma unroll
    for (int nt = 0; nt < 4; ++nt)
#pragma unroll
      for (int r = 0; r < 4; ++r) mx = fmaxf(mx, s[nt][r]);
    mx = fmaxf(mx, __shfl_xor(mx, 16));
    mx = fmaxf(mx, __shfl_xor(mx, 32));
    unsigned long long grow = __ballot(mx > mst + 8.0f);
    if (grow) {  // wave-uniform
      float mnew = fmaxf(mst, mx);
      float al = exp2f((mst - mnew) * LOG2E);
      mst = mnew;
      lst *= al;
#pragma unroll
      for (int nt = 0; nt < 8; ++nt)
#pragma unroll
        for (int r = 0; r < 4; ++r) oacc[nt][r] *= al;
    }
    float ps = 0.f;
#pragma unroll
    for (int nt = 0; nt < 4; ++nt)
#pragma unroll
      for (int r = 0; r < 4; ++r) {
        float p = exp2f((s[nt][r] - mst) * LOG2E);
        s[nt][r] = p;
        ps += p;
      }
    ps += __shfl_xor(ps, 16);
    ps += __shfl_xor(ps, 32);
    lst += ps;

    // P pack -> LDS P[qrow][key], dual b32 stores (dword slot by quad>>1)
    {
      int dsel = quad >> 1;
#pragma unroll
      for (int nt = 0; nt < 4; ++nt) {
        int pc = (nt * 2 + dsel) ^ (l16 & 7);
        u32 wlo = cvtpk(s[nt][0], s[nt][1]);
        u32 whi = cvtpk(s[nt][2], s[nt][3]);
        u16* base = &lds[pbase + l16 * 64 + pc * 8 + (quad & 1) * 4];
        ds_write32(base + 2 * dsel, dsel ? whi : wlo);
        ds_write32(base + 2 * (1 - dsel), dsel ? wlo : whi);
      }
    }
    __syncthreads();  // A: all QK reads of K(ti) done; P ordered; V(ti) resident
    if (ti + 1 < 32) stageK((ti + 1) * 64);  // overlaps PV

    // O^T += Vtile^T * P^T
#pragma unroll
    for (int ks = 0; ks < 2; ++ks) {
      bf16x8 pf = ld8(&lds[pbase + l16 * 64 + (((ks * 4 + quad) ^ (l16 & 7)) * 8)]);
#pragma unroll
      for (int nt = 0; nt < 8; ++nt) {
        int dim = nt * 16 + l16;
        bf16x8 vf = ld8(&lds[8192 + dim * 64 + (((ks * 4 + quad) ^ (l16 & 7)) * 8)]);
        oacc[nt] = __builtin_amdgcn_mfma_f32_16x16x32_bf16(vf, pf, oacc[nt], 0, 0, 0);
      }
    }
    __syncthreads();  // B: all PV reads of V(ti) done; K(ti+1) DMA drained
    if (ti + 1 < 32) stageV((ti + 1) * 64);  // overlaps next QK + softmax
  }

  // normalize by l (per-lane scalar)
  {
    float inv = 1.0f / lst;
#pragma unroll
    for (int nt = 0; nt < 8; ++nt)
#pragma unroll
      for (int r = 0; r < 4; ++r) oacc[nt][r] *= inv;
  }

  // combine: comp1 waves dump normalized O2^T (f32x4) to LDS; comp0 diff+RMS+store
  float* cb = (float*)lds;  // 32 rows x 132 floats: cb[qrow][dim]
  if (comp == 1) {
    int rowc = rh + l16;
#pragma unroll
    for (int nt = 0; nt < 8; ++nt)
      *(f32x4*)(&cb[rowc * 132 + nt * 16 + quad * 4]) = oacc[nt];
  }
  __syncthreads();
  if (comp == 0) {
    const bool f32 = flag[0] == 0;
    float lam = lamp[0];
    int rowc = rh + l16;
    float dv[8][4];
    float sq = 0.f;
#pragma unroll
    for (int nt = 0; nt < 8; ++nt) {
      f32x4 c2 = *(const f32x4*)(&cb[rowc * 132 + nt * 16 + quad * 4]);
#pragma unroll
      for (int r = 0; r < 4; ++r) {
        float d = oacc[nt][r] - lam * c2[r];
        dv[nt][r] = d;
        sq += d * d;
      }
    }
    sq += __shfl_xor(sq, 16);
    sq += __shfl_xor(sq, 32);
    float rms = rsqrtf(sq * (1.0f / 128.0f) + 1e-5f);
    size_t rowg = (size_t)(b * 2048 + q0 + rowc) * 1024 + h * 128;
#pragma unroll
    for (int nt = 0; nt < 8; ++nt) {
      float v0 = dv[nt][0] * rms * ldf(subw, nt * 16 + quad * 4 + 0, f32) * ONE_MINUS_LAM_INIT;
      float v1 = dv[nt][1] * rms * ldf(subw, nt * 16 + quad * 4 + 1, f32) * ONE_MINUS_LAM_INIT;
      float v2 = dv[nt][2] * rms * ldf(subw, nt * 16 + quad * 4 + 2, f32) * ONE_MINUS_LAM_INIT;
      float v3 = dv[nt][3] * rms * ldf(subw, nt * 16 + quad * 4 + 3, f32) * ONE_MINUS_LAM_INIT;
      u32x2 pk2 = {cvtpk(v0, v1), cvtpk(v2, v3)};
      *(u32x2*)(o + rowg + nt * 16 + quad * 4) = pk2;
    }
  }
}

// ---------------- host ----------------
extern "C" void kernel_launch(void* const* d_in, const int* in_sizes, int n_in,
                              void* d_out, int out_size, void* d_ws, size_t ws_size,
                              hipStream_t stream) {
  (void)in_sizes; (void)n_in; (void)out_size; (void)ws_size;
  const void* x = d_in[0];
  const void* ln1w = d_in[1];
  const void* ln1b = d_in[2];
  const void* Wq = d_in[3];
  const void* Wk = d_in[4];
  const void* Wv = d_in[5];
  const void* Wo = d_in[6];
  const void* lq1 = d_in[7];
  const void* lk1 = d_in[8];
  const void* lq2 = d_in[9];
  const void* lk2 = d_in[10];
  const void* subw = d_in[11];
  const void* ln2w = d_in[12];
  const void* ln2b = d_in[13];
  const void* W1 = d_in[14];
  const void* b1 = d_in[15];
  const void* W2 = d_in[16];
  const void* b2 = d_in[17];

  char* ws = (char*)d_ws;
  const size_t MB = 1u << 20;
  u16* A = (u16*)ws;               // h1 -> ob -> h2
  u16* B = (u16*)(ws + 8 * MB);    // q -> g (16MB contiguous over B+C)
  u16* C = (u16*)(ws + 16 * MB);   // k -> g(hi)
  u16* D = (u16*)(ws + 24 * MB);   // vT -> WoT -> W1Th|W2Th
  u16* E = (u16*)(ws + 32 * MB);   // WqT|WkT|WvT -> x2
  float* lam = (float*)(ws + 40 * MB);
  int* flag = (int*)(ws + 40 * MB + 64);
  u16* W2Th = D + 2097152;

  detect_kernel<<<dim3(1), dim3(64), 0, stream>>>((const u32*)x, flag);
  lam_kernel<<<dim3(1), dim3(64), 0, stream>>>(lq1, lk1, lq2, lk2, flag, lam);
  ln_kernel<true><<<dim3(1024), dim3(256), 0, stream>>>(x, ln1w, ln1b, flag, A);

  // Wq|Wk|Wv -> E concatenated n-major (3072 x 1024)
  twc_kernel<<<dim3(16, 16, 3), dim3(256), 0, stream>>>(Wq, Wk, Wv, E, 1024, 1024, 0,
                                                        1048576, flag);
  // fused q/k/v projection: q->B (pre-scaled), k->C, vT->D
  gemm_bt<64, EP_QKV, false, false><<<dim3(24, 64), dim3(256), 0, stream>>>(
      A, E, B, 4096, 3072, 1024, nullptr, 0, nullptr, flag, C, D);

  attn_kernel<<<dim3(1024), dim3(256), 0, stream>>>(B, C, D, lam, subw, flag, A);

  // WoT -> D (vT dead); x2(bf16) = ob @ Wo + x -> E (Wq..WvT dead)
  twc_kernel<<<dim3(16, 16, 1), dim3(256), 0, stream>>>(Wo, Wo, Wo, D, 1024, 1024, 0, 0,
                                                        flag);
  gemm_bt<64, EP_RES, true, false><<<dim3(8, 64), dim3(256), 0, stream>>>(
      A, D, E, 4096, 1024, 1024, nullptr, 0, x, flag, nullptr, nullptr);
  ln_kernel<false><<<dim3(1024), dim3(256), 0, stream>>>(E, ln2w, ln2b, flag, A);

  // FFN in two FF-column halves; g = B..C (16MB contiguous), full-M launches
  for (int hh = 0; hh < 2; ++hh) {
    twc_kernel<<<dim3(32, 16, 1), dim3(256), 0, stream>>>(W1, W1, W1, D, 4096, 1024,
                                                          (size_t)hh * 2048, 0, flag);
    twc_kernel<<<dim3(16, 32, 1), dim3(256), 0, stream>>>(
        W2, W2, W2, W2Th, 1024, 2048, (size_t)hh * 2048 * 1024, 0, flag);
    gemm_bt<128, EP_GELU, false, false><<<dim3(16, 32), dim3(256), 0, stream>>>(
        A, D, B, 4096, 2048, 1024, b1, hh * 2048, nullptr, flag, nullptr, nullptr);
    if (hh == 0) {
      gemm_bt<64, EP_BIASRES, false, true><<<dim3(8, 64), dim3(256), 0, stream>>>(
          B, W2Th, d_out, 4096, 1024, 2048, b2, 0, E, flag, nullptr, nullptr);
    } else {
      gemm_bt<64, EP_RES, true, true><<<dim3(8, 64), dim3(256), 0, stream>>>(
          B, W2Th, d_out, 4096, 1024, 2048, nullptr, 0, d_out, flag, nullptr, nullptr);
    }
  }
}

// Round 3
// 478.656 us; speedup vs baseline: 1.0686x; 1.0686x over previous
//
#include <hip/hip_runtime.h>

// DiffAttnLayer: B=2,N=2048,EMB=1024,H=8,HD=64,FF=4096.
// Inputs fp32 (runtime-detected); output dtype follows input dtype.
// R11 = R9 structure (64-row q-tiles, 32 rows/wave — best LDS amortization;
// R10's 32-row tiles doubled staging+LDS reads and regressed) plus:
//  - defer-max (THR=8, validated R10): skip rescale chain on non-growing tiles
//  - exp2 via fmaf with cached mstl = mst*LOG2E (1 op/elem instead of 2)
//  - bijective XCD remap (validated R10: FETCH 70->12MB, K/V L2-resident)
// Bank-conflict counter (~2.1M) is understood: 2-way l16/l16+8 phase aliasing,
// identical under all P-pack forms, time-cheap (m136) — not chased.
// Workspace: 5 x 8MB slots + scalars @40MB:
//  A: h1 -> ob -> h2        B: q -> g(lo)      C: k -> g(hi)
//  D: vT -> WoT -> W1Th|W2Th                   E: WqT|WkT|WvT -> x2

typedef unsigned short u16;
typedef unsigned int u32;
typedef __attribute__((ext_vector_type(8))) __bf16 bf16x8;
typedef __attribute__((ext_vector_type(4))) float f32x4;
typedef __attribute__((ext_vector_type(4))) u32 u32x4;
typedef __attribute__((ext_vector_type(2))) u32 u32x2;

#define LOG2E 1.4426950408889634f
#define LAM_INIT 0.355509068f
#define ONE_MINUS_LAM_INIT 0.644490932f

__device__ __forceinline__ float bf2f(u16 x) {
  u32 u = ((u32)x) << 16;
  return __builtin_bit_cast(float, u);
}
__device__ __forceinline__ u16 f2bf(float f) {
  u32 u = __builtin_bit_cast(u32, f);
  u32 r = (u + 0x7FFFu + ((u >> 16) & 1u)) >> 16;
  return (u16)r;
}
__device__ __forceinline__ u32 cvtpk(float lo, float hi) {
  u32 r;
  asm("v_cvt_pk_bf16_f32 %0, %1, %2" : "=v"(r) : "v"(lo), "v"(hi));
  return r;
}
__device__ __forceinline__ float ldf(const void* p, size_t i, bool f32) {
  return f32 ? ((const float*)p)[i] : bf2f(((const u16*)p)[i]);
}
// global -> LDS async DMA, 16B/lane; LDS dest = wave-uniform base + lane*16.
__device__ __forceinline__ void async16(const u16* g, u16* l) {
  __builtin_amdgcn_global_load_lds((const __attribute__((address_space(1))) u32*)g,
                                   (__attribute__((address_space(3))) u32*)l, 16, 0, 0);
}
__device__ __forceinline__ bf16x8 ld8(const u16* p) { return *(const bf16x8*)p; }

// ---------------- input-dtype detector (1 = bf16, 0 = fp32) ----------------
__global__ void detect_kernel(const u32* x, int* flag) {
  int e = (x[threadIdx.x] >> 7) & 0xFF;
  unsigned long long m = __ballot(e >= 90 && e <= 150);
  if (threadIdx.x == 0) flag[0] = (__popcll(m) >= 40) ? 1 : 0;
}

// ---------------- lambda ----------------
__global__ void lam_kernel(const void* lq1, const void* lk1, const void* lq2,
                           const void* lk2, const int* flag, float* out) {
  const bool f32 = flag[0] == 0;
  int L = threadIdx.x;
  float a = ldf(lq1, L, f32) * ldf(lk1, L, f32);
  float c = ldf(lq2, L, f32) * ldf(lk2, L, f32);
#pragma unroll
  for (int m = 1; m < 64; m <<= 1) { a += __shfl_xor(a, m); c += __shfl_xor(c, m); }
  if (L == 0) out[0] = __expf(a) - __expf(c) + LAM_INIT;
}

// ---------------- LayerNorm over 1024, one wave per row ----------------
__device__ __forceinline__ void unpack8(u32x4 u, float* f) {
#pragma unroll
  for (int i = 0; i < 4; ++i) {
    f[2 * i] = bf2f((u16)(u[i] & 0xffffu));
    f[2 * i + 1] = bf2f((u16)(u[i] >> 16));
  }
}

template <bool XRAW>
__global__ __launch_bounds__(256) void ln_kernel(const void* __restrict__ x,
                                                 const void* __restrict__ w,
                                                 const void* __restrict__ b,
                                                 const int* __restrict__ flag,
                                                 u16* __restrict__ out) {
  const bool f32 = flag[0] == 0;
  const int row = blockIdx.x * 4 + (threadIdx.x >> 6);
  const int L = threadIdx.x & 63;
  float xv[16];
  if (XRAW && f32) {
    const f32x4* xr = (const f32x4*)((const float*)x + (size_t)row * 1024 + L * 16);
#pragma unroll
    for (int i = 0; i < 4; ++i) {
      f32x4 vv = xr[i];
#pragma unroll
      for (int j = 0; j < 4; ++j) xv[i * 4 + j] = vv[j];
    }
  } else {
    const u16* xr = (const u16*)x + (size_t)row * 1024 + L * 16;
    unpack8(*(const u32x4*)xr, xv);
    unpack8(*(const u32x4*)(xr + 8), xv + 8);
  }
  float s = 0.f, sq = 0.f;
#pragma unroll
  for (int i = 0; i < 16; ++i) { s += xv[i]; sq += xv[i] * xv[i]; }
#pragma unroll
  for (int m = 1; m < 64; m <<= 1) { s += __shfl_xor(s, m); sq += __shfl_xor(sq, m); }
  float mean = s * (1.0f / 1024.0f);
  float var = sq * (1.0f / 1024.0f) - mean * mean;
  float rstd = rsqrtf(var + 1e-5f);
  u32 pk[8];
#pragma unroll
  for (int i = 0; i < 8; ++i) {
    float w0 = ldf(w, L * 16 + 2 * i, f32), w1 = ldf(w, L * 16 + 2 * i + 1, f32);
    float b0 = ldf(b, L * 16 + 2 * i, f32), b1v = ldf(b, L * 16 + 2 * i + 1, f32);
    float v0 = (xv[2 * i] - mean) * rstd * w0 + b0;
    float v1 = (xv[2 * i + 1] - mean) * rstd * w1 + b1v;
    pk[i] = (u32)f2bf(v0) | ((u32)f2bf(v1) << 16);
  }
  u32x4 o0 = {pk[0], pk[1], pk[2], pk[3]};
  u32x4 o1 = {pk[4], pk[5], pk[6], pk[7]};
  *(u32x4*)(out + (size_t)row * 1024 + L * 16) = o0;
  *(u32x4*)(out + (size_t)row * 1024 + L * 16 + 8) = o1;
}

// -------- transpose+convert: dst[z][c][r] = (bf16)src_z[r][c], z-multiplexed --------
__global__ __launch_bounds__(256) void twc_kernel(const void* __restrict__ s0,
                                                  const void* __restrict__ s1,
                                                  const void* __restrict__ s2,
                                                  u16* __restrict__ dst, int sstride,
                                                  int dstride, size_t soff, size_t dzoff,
                                                  const int* __restrict__ flag) {
  __shared__ __align__(16) u16 tile[64][72];
  const bool f32 = flag[0] == 0;
  const void* src = blockIdx.z == 0 ? s0 : (blockIdx.z == 1 ? s1 : s2);
  u16* dz = dst + (size_t)blockIdx.z * dzoff;
  const int r0 = blockIdx.y * 64, c0 = blockIdx.x * 64;
  const int t = threadIdx.x;
  const int rr = t >> 3, cc = t & 7;
#pragma unroll
  for (int i = 0; i < 2; ++i) {
    int row = rr + i * 32;
    size_t idx = (size_t)(r0 + row) * sstride + c0 + cc * 8 + soff;
    if (f32) {
      const f32x4* s = (const f32x4*)((const float*)src + idx);
      f32x4 a = s[0], b = s[1];
      union { u16 t16[8]; u32x4 v; } u_;
#pragma unroll
      for (int j = 0; j < 4; ++j) { u_.t16[j] = f2bf(a[j]); u_.t16[4 + j] = f2bf(b[j]); }
      *(u32x4*)(&tile[row][cc * 8]) = u_.v;
    } else {
      *(u32x4*)(&tile[row][cc * 8]) = *(const u32x4*)((const u16*)src + idx);
    }
  }
  __syncthreads();
  u16* d = dz + (size_t)c0 * dstride + r0;
#pragma unroll
  for (int i = 0; i < 2; ++i) {
    int n = rr + i * 32;
    union { u16 t16[8]; u32x4 v; } u_;
#pragma unroll
    for (int j = 0; j < 8; ++j) u_.t16[j] = tile[cc * 8 + j][n];
    *(u32x4*)(d + (size_t)n * dstride + cc * 8) = u_.v;
  }
}

// ------------- GEMM: C(MxN) = A(MxK) * Bt(NxK)^T, tile TM x 128 --------------
enum { EP_NONE = 0, EP_RES = 2, EP_GELU = 3, EP_BIASRES = 4, EP_QKV = 5 };

template <int TM, int EPI, bool RESRAW, bool OUTFLEX>
__global__ __launch_bounds__(256, 2) void gemm_bt(
    const u16* __restrict__ A, const u16* __restrict__ Bt, void* __restrict__ Cv,
    int M, int N, int K, const void* __restrict__ bias, int boff,
    const void* __restrict__ res, const int* __restrict__ flag,
    u16* __restrict__ kout, u16* __restrict__ vtout) {
  constexpr int MT = TM / 32;  // acc tiles per wave in M
  __shared__ __align__(16) u16 lds[TM * 64 + 128 * 64];
  const int t = threadIdx.x;
  const int w = t >> 6, L = t & 63;
  const int quad = L >> 4, l16 = L & 15;
  const int m0 = blockIdx.y * TM, n0 = blockIdx.x * 128;
  const int wm = (TM == 128) ? (w >> 1) * 64 : (w & 1) * 32;
  const int wn = (TM == 128) ? (w & 1) * 64 : (w >> 1) * 64;
  const int srow = L >> 3, spc = L & 7;
  const int sc = spc ^ srow;
  constexpr int BBASE = TM * 64;

  f32x4 acc[MT][4] = {};
  const u16* Ab = A + (size_t)m0 * K;
  const u16* Bb = Bt + (size_t)n0 * K;

  for (int kt = 0; kt < K; kt += 64) {
#pragma unroll
    for (int r = 0; r < TM / 32; ++r) {
      int row = r * 32 + w * 8 + srow;
      async16(Ab + (size_t)row * K + kt + sc * 8, &lds[row * 64 + spc * 8]);
    }
#pragma unroll
    for (int r = 0; r < 4; ++r) {
      int row = r * 32 + w * 8 + srow;
      async16(Bb + (size_t)row * K + kt + sc * 8, &lds[BBASE + row * 64 + spc * 8]);
    }
    __syncthreads();
#pragma unroll
    for (int ks = 0; ks < 2; ++ks) {
      bf16x8 af[MT], bfr[4];
#pragma unroll
      for (int mt = 0; mt < MT; ++mt) {
        int row = wm + mt * 16 + l16;
        af[mt] = ld8(&lds[row * 64 + (((ks * 4 + quad) ^ (l16 & 7)) * 8)]);
      }
#pragma unroll
      for (int nt = 0; nt < 4; ++nt) {
        int row = wn + nt * 16 + l16;
        bfr[nt] = ld8(&lds[BBASE + row * 64 + (((ks * 4 + quad) ^ (l16 & 7)) * 8)]);
      }
#pragma unroll
      for (int mt = 0; mt < MT; ++mt)
#pragma unroll
        for (int nt = 0; nt < 4; ++nt)
          acc[mt][nt] =
              __builtin_amdgcn_mfma_f32_16x16x32_bf16(af[mt], bfr[nt], acc[mt][nt], 0, 0, 0);
    }
    __syncthreads();
  }

  const bool f32 = flag[0] == 0;
#pragma unroll
  for (int mt = 0; mt < MT; ++mt) {
#pragma unroll
    for (int nt = 0; nt < 4; ++nt) {
      int col = n0 + wn + nt * 16 + l16;
      float bv = 0.f;
      if (EPI == EP_GELU || EPI == EP_BIASRES) bv = ldf(bias, (size_t)boff + col, f32);
#pragma unroll
      for (int r = 0; r < 4; ++r) {
        int row = m0 + wm + mt * 16 + quad * 4 + r;
        float v = acc[mt][nt][r];
        if (EPI == EP_GELU) {
          v += bv;
          v = 0.5f * v * (1.0f + erff(v * 0.70710678118654752f));
        }
        if (EPI == EP_RES || EPI == EP_BIASRES) {
          size_t ri = (size_t)row * N + col;
          float rv = RESRAW ? ldf(res, ri, f32) : bf2f(((const u16*)res)[ri]);
          v += rv;
          if (EPI == EP_BIASRES) v += bv;
        }
        if (EPI == EP_QKV) {
          if (col < 1024) {
            ((u16*)Cv)[(size_t)row * 1024 + col] = f2bf(v * 0.125f);  // q, pre-scaled
          } else if (col < 2048) {
            kout[(size_t)row * 1024 + (col - 1024)] = f2bf(v);  // k
          } else {  // v stored transposed: vT[(b*8+h)*128+d][2048]
            int c2 = col - 2048;
            int bb = row >> 11, n = row & 2047, hh = c2 >> 7, d = c2 & 127;
            vtout[(size_t)((bb * 8 + hh) * 128 + d) * 2048 + n] = f2bf(v);
          }
        } else {
          size_t ci = (size_t)row * N + col;
          if (OUTFLEX && f32)
            ((float*)Cv)[ci] = v;
          else
            ((u16*)Cv)[ci] = f2bf(v);
        }
      }
    }
  }
}

// ---------------- Flash differential attention (R9 structure + defer-max) ----------
// grid 512 = b(2) x h(8) x qtile(32 of 64 rows), XCD-remapped. 4 waves:
// comp=w>>1, rh=(w&1)*32 (32 q-rows per wave, 2 mt of 16).
// LDS (u16): K[2][64][64] @0 | Vt[128][64] @8192 | P/Qstage[4][32][64] @16384
// S^T = mfma(K,Q): lane owns qrow l16 per mt. O^T = mfma(vT,P^T).
// Defer-max (THR=8): skip the mnew/al/rescale chain unless row-max grows >8.
// exp2 via fmaf with cached mstl = mst*LOG2E.
// 2 barriers/tile: stageK overlaps PV, stageV overlaps QK+softmax.
__global__ __launch_bounds__(256, 2) void attn_kernel(
    const u16* __restrict__ q, const u16* __restrict__ k, const u16* __restrict__ vT,
    const float* __restrict__ lamp, const void* __restrict__ subw,
    const int* __restrict__ flag, u16* __restrict__ o) {
  __shared__ __align__(16) u16 lds[24576];
  const int t = threadIdx.x, w = t >> 6, L = t & 63;
  const int quad = L >> 4, l16 = L & 15;
  // bijective XCD remap (512 = 8 x 64): XCD x keeps (b,h) pairs {2x,2x+1}
  const int bid = ((blockIdx.x & 7) << 6) | (blockIdx.x >> 3);
  const int qt = bid & 31, h = (bid >> 5) & 7, b = bid >> 8;
  const int q0 = qt * 64;
  const int comp = w >> 1, rh = (w & 1) * 32;
  const int srow = L >> 3, spc = L & 7, sc = spc ^ srow;
  const u16* vb = vT + (size_t)(b * 8 + h) * (128 * 2048);
  const int pbase = 16384 + w * 2048;

  auto stageK = [&](int kt) {
#pragma unroll
    for (int r = 0; r < 4; ++r) {
      int row = r * 32 + w * 8 + srow;  // comp=row>>6, key=row&63
      int c_ = row >> 6, key = row & 63;
      async16(k + ((size_t)(b * 2048 + kt + key) * 1024 + (2 * h + c_) * 64 + sc * 8),
              &lds[row * 64 + spc * 8]);
    }
  };
  auto stageV = [&](int kt) {
#pragma unroll
    for (int r = 0; r < 4; ++r) {
      int dim = r * 32 + w * 8 + srow;  // 0..127
      async16(vb + (size_t)dim * 2048 + kt + sc * 8, &lds[8192 + dim * 64 + spc * 8]);
    }
  };

  stageK(0);
  stageV(0);
  // stage Q (both comps) into P region
#pragma unroll
  for (int r = 0; r < 4; ++r) {
    int row = r * 32 + w * 8 + srow;  // 0..127 : comp=row>>6, qrow=row&63
    int c_ = row >> 6, qr = row & 63;
    async16(q + ((size_t)(b * 2048 + q0 + qr) * 1024 + (2 * h + c_) * 64 + sc * 8),
            &lds[16384 + row * 64 + spc * 8]);
  }
  __syncthreads();  // all initial DMA (K0, V0, Q) drained
  bf16x8 qf[2][2];
#pragma unroll
  for (int mt = 0; mt < 2; ++mt)
#pragma unroll
    for (int ks = 0; ks < 2; ++ks) {
      int row = rh + mt * 16 + l16;
      qf[mt][ks] =
          ld8(&lds[16384 + comp * 4096 + row * 64 + (((ks * 4 + quad) ^ (l16 & 7)) * 8)]);
    }
  // no barrier: each wave's qf rows == its own (later) P rows; in-wave DS order

  float mst[2] = {-1.0e30f, -1.0e30f};
  float mstl[2] = {-1.0e30f, -1.0e30f};
  float lst[2] = {0.f, 0.f};
  f32x4 oacc[8][2] = {};

  for (int ti = 0; ti < 32; ++ti) {
    // S^T = Ktile * Q^T for own comp; lane owns qrow = l16 (per mt tile)
    f32x4 s[4][2] = {};
#pragma unroll
    for (int ks = 0; ks < 2; ++ks) {
      bf16x8 kf[4];
#pragma unroll
      for (int nt = 0; nt < 4; ++nt) {
        int row = nt * 16 + l16;
        kf[nt] = ld8(&lds[comp * 4096 + row * 64 + (((ks * 4 + quad) ^ (l16 & 7)) * 8)]);
      }
#pragma unroll
      for (int nt = 0; nt < 4; ++nt)
#pragma unroll
        for (int mt = 0; mt < 2; ++mt)
          s[nt][mt] = __builtin_amdgcn_mfma_f32_16x16x32_bf16(kf[nt], qf[mt][ks], s[nt][mt], 0, 0, 0);
    }

    // online softmax with defer-max: per-lane qrow, 2 shfl per reduce
#pragma unroll
    for (int mt = 0; mt < 2; ++mt) {
      float mx = -3.0e38f;
#pragma unroll
      for (int nt = 0; nt < 4; ++nt)
#pragma unroll
        for (int r = 0; r < 4; ++r) mx = fmaxf(mx, s[nt][mt][r]);
      mx = fmaxf(mx, __shfl_xor(mx, 16));
      mx = fmaxf(mx, __shfl_xor(mx, 32));
      if (__ballot(mx > mst[mt] + 8.0f)) {  // wave-uniform
        float mnew = fmaxf(mst[mt], mx);
        float al = exp2f((mst[mt] - mnew) * LOG2E);
        mst[mt] = mnew;
        mstl[mt] = mnew * LOG2E;
        lst[mt] *= al;
#pragma unroll
        for (int nt = 0; nt < 8; ++nt)
#pragma unroll
          for (int r = 0; r < 4; ++r) oacc[nt][mt][r] *= al;
      }
      float ps = 0.f;
#pragma unroll
      for (int nt = 0; nt < 4; ++nt)
#pragma unroll
        for (int r = 0; r < 4; ++r) {
          float p = exp2f(__builtin_fmaf(s[nt][mt][r], LOG2E, -mstl[mt]));
          s[nt][mt][r] = p;
          ps += p;
        }
      ps += __shfl_xor(ps, 16);
      ps += __shfl_xor(ps, 32);
      lst[mt] += ps;
    }

    // P pack -> LDS P[qrow][key] (B-operand readable), wave-private region.
    // 4 consecutive keys per lane per (mt,nt): 2x cvt_pk + one b64 write.
#pragma unroll
    for (int mt = 0; mt < 2; ++mt) {
      int prow = mt * 16 + l16;
#pragma unroll
      for (int nt = 0; nt < 4; ++nt) {
        int pc = (nt * 2 + (quad >> 1)) ^ (l16 & 7);
        u32x2 pk2 = {cvtpk(s[nt][mt][0], s[nt][mt][1]), cvtpk(s[nt][mt][2], s[nt][mt][3])};
        *(u32x2*)(&lds[pbase + prow * 64 + pc * 8 + (quad & 1) * 4]) = pk2;
      }
    }
    __syncthreads();  // A: all QK reads of K(ti) done; P ordered; V(ti) resident
    if (ti + 1 < 32) stageK((ti + 1) * 64);  // overlaps PV

    // O^T += Vtile^T * P^T
#pragma unroll
    for (int ks = 0; ks < 2; ++ks) {
      bf16x8 pf[2];
#pragma unroll
      for (int mt = 0; mt < 2; ++mt) {
        int row = mt * 16 + l16;
        pf[mt] = ld8(&lds[pbase + row * 64 + (((ks * 4 + quad) ^ (l16 & 7)) * 8)]);
      }
#pragma unroll
      for (int nt = 0; nt < 8; ++nt) {
        int dim = nt * 16 + l16;
        bf16x8 vf = ld8(&lds[8192 + dim * 64 + (((ks * 4 + quad) ^ (l16 & 7)) * 8)]);
#pragma unroll
        for (int mt = 0; mt < 2; ++mt)
          oacc[nt][mt] = __builtin_amdgcn_mfma_f32_16x16x32_bf16(vf, pf[mt], oacc[nt][mt], 0, 0, 0);
      }
    }
    __syncthreads();  // B: all PV reads of V(ti) done; K(ti+1) DMA drained
    if (ti + 1 < 32) stageV((ti + 1) * 64);  // overlaps next QK + softmax
  }

  // normalize by l (per-lane scalar per mt)
#pragma unroll
  for (int mt = 0; mt < 2; ++mt) {
    float inv = 1.0f / lst[mt];
#pragma unroll
    for (int nt = 0; nt < 8; ++nt)
#pragma unroll
      for (int r = 0; r < 4; ++r) oacc[nt][mt][r] *= inv;
  }

  // combine: comp1 waves dump normalized O2^T (f32x4) to LDS; comp0 diff+RMS+store
  float* cb = (float*)lds;  // 64 rows x 132 floats: cb[qrow][dim]
  if (comp == 1) {
#pragma unroll
    for (int mt = 0; mt < 2; ++mt) {
      int rowc = rh + mt * 16 + l16;
#pragma unroll
      for (int nt = 0; nt < 8; ++nt)
        *(f32x4*)(&cb[rowc * 132 + nt * 16 + quad * 4]) = oacc[nt][mt];
    }
  }
  __syncthreads();
  if (comp == 0) {
    const bool f32 = flag[0] == 0;
    float lam = lamp[0];
    float sw[8][4];
#pragma unroll
    for (int nt = 0; nt < 8; ++nt)
#pragma unroll
      for (int r = 0; r < 4; ++r) sw[nt][r] = ldf(subw, nt * 16 + quad * 4 + r, f32);
#pragma unroll
    for (int mt = 0; mt < 2; ++mt) {
      int rowc = rh + mt * 16 + l16;
      float dv[8][4];
      float sq = 0.f;
#pragma unroll
      for (int nt = 0; nt < 8; ++nt) {
        f32x4 c2 = *(const f32x4*)(&cb[rowc * 132 + nt * 16 + quad * 4]);
#pragma unroll
        for (int r = 0; r < 4; ++r) {
          float d = oacc[nt][mt][r] - lam * c2[r];
          dv[nt][r] = d;
          sq += d * d;
        }
      }
      sq += __shfl_xor(sq, 16);
      sq += __shfl_xor(sq, 32);
      float rms = rsqrtf(sq * (1.0f / 128.0f) + 1e-5f);
      size_t rowg = (size_t)(b * 2048 + q0 + rowc) * 1024 + h * 128;
#pragma unroll
      for (int nt = 0; nt < 8; ++nt) {
        float v0 = dv[nt][0] * rms * sw[nt][0] * ONE_MINUS_LAM_INIT;
        float v1 = dv[nt][1] * rms * sw[nt][1] * ONE_MINUS_LAM_INIT;
        float v2 = dv[nt][2] * rms * sw[nt][2] * ONE_MINUS_LAM_INIT;
        float v3 = dv[nt][3] * rms * sw[nt][3] * ONE_MINUS_LAM_INIT;
        u32x2 pk2 = {cvtpk(v0, v1), cvtpk(v2, v3)};
        *(u32x2*)(o + rowg + nt * 16 + quad * 4) = pk2;
      }
    }
  }
}

// ---------------- host ----------------
extern "C" void kernel_launch(void* const* d_in, const int* in_sizes, int n_in,
                              void* d_out, int out_size, void* d_ws, size_t ws_size,
                              hipStream_t stream) {
  (void)in_sizes; (void)n_in; (void)out_size; (void)ws_size;
  const void* x = d_in[0];
  const void* ln1w = d_in[1];
  const void* ln1b = d_in[2];
  const void* Wq = d_in[3];
  const void* Wk = d_in[4];
  const void* Wv = d_in[5];
  const void* Wo = d_in[6];
  const void* lq1 = d_in[7];
  const void* lk1 = d_in[8];
  const void* lq2 = d_in[9];
  const void* lk2 = d_in[10];
  const void* subw = d_in[11];
  const void* ln2w = d_in[12];
  const void* ln2b = d_in[13];
  const void* W1 = d_in[14];
  const void* b1 = d_in[15];
  const void* W2 = d_in[16];
  const void* b2 = d_in[17];

  char* ws = (char*)d_ws;
  const size_t MB = 1u << 20;
  u16* A = (u16*)ws;               // h1 -> ob -> h2
  u16* B = (u16*)(ws + 8 * MB);    // q -> g (16MB contiguous over B+C)
  u16* C = (u16*)(ws + 16 * MB);   // k -> g(hi)
  u16* D = (u16*)(ws + 24 * MB);   // vT -> WoT -> W1Th|W2Th
  u16* E = (u16*)(ws + 32 * MB);   // WqT|WkT|WvT -> x2
  float* lam = (float*)(ws + 40 * MB);
  int* flag = (int*)(ws + 40 * MB + 64);
  u16* W2Th = D + 2097152;

  detect_kernel<<<dim3(1), dim3(64), 0, stream>>>((const u32*)x, flag);
  lam_kernel<<<dim3(1), dim3(64), 0, stream>>>(lq1, lk1, lq2, lk2, flag, lam);
  ln_kernel<true><<<dim3(1024), dim3(256), 0, stream>>>(x, ln1w, ln1b, flag, A);

  // Wq|Wk|Wv -> E concatenated n-major (3072 x 1024)
  twc_kernel<<<dim3(16, 16, 3), dim3(256), 0, stream>>>(Wq, Wk, Wv, E, 1024, 1024, 0,
                                                        1048576, flag);
  // fused q/k/v projection: q->B (pre-scaled), k->C, vT->D
  gemm_bt<64, EP_QKV, false, false><<<dim3(24, 64), dim3(256), 0, stream>>>(
      A, E, B, 4096, 3072, 1024, nullptr, 0, nullptr, flag, C, D);

  attn_kernel<<<dim3(512), dim3(256), 0, stream>>>(B, C, D, lam, subw, flag, A);

  // WoT -> D (vT dead); x2(bf16) = ob @ Wo + x -> E (Wq..WvT dead)
  twc_kernel<<<dim3(16, 16, 1), dim3(256), 0, stream>>>(Wo, Wo, Wo, D, 1024, 1024, 0, 0,
                                                        flag);
  gemm_bt<64, EP_RES, true, false><<<dim3(8, 64), dim3(256), 0, stream>>>(
      A, D, E, 4096, 1024, 1024, nullptr, 0, x, flag, nullptr, nullptr);
  ln_kernel<false><<<dim3(1024), dim3(256), 0, stream>>>(E, ln2w, ln2b, flag, A);

  // FFN in two FF-column halves; g = B..C (16MB contiguous), full-M launches
  for (int hh = 0; hh < 2; ++hh) {
    twc_kernel<<<dim3(32, 16, 1), dim3(256), 0, stream>>>(W1, W1, W1, D, 4096, 1024,
                                                          (size_t)hh * 2048, 0, flag);
    twc_kernel<<<dim3(16, 32, 1), dim3(256), 0, stream>>>(
        W2, W2, W2, W2Th, 1024, 2048, (size_t)hh * 2048 * 1024, 0, flag);
    gemm_bt<128, EP_GELU, false, false><<<dim3(16, 32), dim3(256), 0, stream>>>(
        A, D, B, 4096, 2048, 1024, b1, hh * 2048, nullptr, flag, nullptr, nullptr);
    if (hh == 0) {
      gemm_bt<64, EP_BIASRES, false, true><<<dim3(8, 64), dim3(256), 0, stream>>>(
          B, W2Th, d_out, 4096, 1024, 2048, b2, 0, E, flag, nullptr, nullptr);
    } else {
      gemm_bt<64, EP_RES, true, true><<<dim3(8, 64), dim3(256), 0, stream>>>(
          B, W2Th, d_out, 4096, 1024, 2048, nullptr, 0, d_out, flag, nullptr, nullptr);
    }
  }
}

// Round 4
// 464.784 us; speedup vs baseline: 1.1005x; 1.0298x over previous
//
#include <hip/hip_runtime.h>

// DiffAttnLayer: B=2,N=2048,EMB=1024,H=8,HD=64,FF=4096.
// Inputs fp32 (runtime-detected); output dtype follows input dtype.
// R12 = R11 + single-barrier double-buffered pipelines (T3-lite):
//  - attn: K/V double-buffered (LDS 48->80KB dynamic; grid caps at 2 blk/CU so
//    free). ONE __syncthreads per tile; its vmcnt(0) drains DMA issued a full
//    tile earlier (~landed). P is wave-private (no barrier, unchanged).
//  - gemm_bt<DB=true> for the 4 grid-512 GEMMs: sync; stage(next); compute(cur).
//    Removes the full-DMA-latency stall every K-step. QKV gemm keeps DB=false
//    (grid 1536 = 6 blk/CU TLP already hides latency; DB would halve occupancy).
// Workspace: 5 x 8MB slots + scalars @40MB:
//  A: h1 -> ob -> h2        B: q -> g(lo)      C: k -> g(hi)
//  D: vT -> WoT -> W1Th|W2Th                   E: WqT|WkT|WvT -> x2

typedef unsigned short u16;
typedef unsigned int u32;
typedef __attribute__((ext_vector_type(8))) __bf16 bf16x8;
typedef __attribute__((ext_vector_type(4))) float f32x4;
typedef __attribute__((ext_vector_type(4))) u32 u32x4;
typedef __attribute__((ext_vector_type(2))) u32 u32x2;

#define LOG2E 1.4426950408889634f
#define LAM_INIT 0.355509068f
#define ONE_MINUS_LAM_INIT 0.644490932f

__device__ __forceinline__ float bf2f(u16 x) {
  u32 u = ((u32)x) << 16;
  return __builtin_bit_cast(float, u);
}
__device__ __forceinline__ u16 f2bf(float f) {
  u32 u = __builtin_bit_cast(u32, f);
  u32 r = (u + 0x7FFFu + ((u >> 16) & 1u)) >> 16;
  return (u16)r;
}
__device__ __forceinline__ u32 cvtpk(float lo, float hi) {
  u32 r;
  asm("v_cvt_pk_bf16_f32 %0, %1, %2" : "=v"(r) : "v"(lo), "v"(hi));
  return r;
}
__device__ __forceinline__ float ldf(const void* p, size_t i, bool f32) {
  return f32 ? ((const float*)p)[i] : bf2f(((const u16*)p)[i]);
}
// global -> LDS async DMA, 16B/lane; LDS dest = wave-uniform base + lane*16.
__device__ __forceinline__ void async16(const u16* g, u16* l) {
  __builtin_amdgcn_global_load_lds((const __attribute__((address_space(1))) u32*)g,
                                   (__attribute__((address_space(3))) u32*)l, 16, 0, 0);
}
__device__ __forceinline__ bf16x8 ld8(const u16* p) { return *(const bf16x8*)p; }

// ---------------- input-dtype detector (1 = bf16, 0 = fp32) ----------------
__global__ void detect_kernel(const u32* x, int* flag) {
  int e = (x[threadIdx.x] >> 7) & 0xFF;
  unsigned long long m = __ballot(e >= 90 && e <= 150);
  if (threadIdx.x == 0) flag[0] = (__popcll(m) >= 40) ? 1 : 0;
}

// ---------------- lambda ----------------
__global__ void lam_kernel(const void* lq1, const void* lk1, const void* lq2,
                           const void* lk2, const int* flag, float* out) {
  const bool f32 = flag[0] == 0;
  int L = threadIdx.x;
  float a = ldf(lq1, L, f32) * ldf(lk1, L, f32);
  float c = ldf(lq2, L, f32) * ldf(lk2, L, f32);
#pragma unroll
  for (int m = 1; m < 64; m <<= 1) { a += __shfl_xor(a, m); c += __shfl_xor(c, m); }
  if (L == 0) out[0] = __expf(a) - __expf(c) + LAM_INIT;
}

// ---------------- LayerNorm over 1024, one wave per row ----------------
__device__ __forceinline__ void unpack8(u32x4 u, float* f) {
#pragma unroll
  for (int i = 0; i < 4; ++i) {
    f[2 * i] = bf2f((u16)(u[i] & 0xffffu));
    f[2 * i + 1] = bf2f((u16)(u[i] >> 16));
  }
}

template <bool XRAW>
__global__ __launch_bounds__(256) void ln_kernel(const void* __restrict__ x,
                                                 const void* __restrict__ w,
                                                 const void* __restrict__ b,
                                                 const int* __restrict__ flag,
                                                 u16* __restrict__ out) {
  const bool f32 = flag[0] == 0;
  const int row = blockIdx.x * 4 + (threadIdx.x >> 6);
  const int L = threadIdx.x & 63;
  float xv[16];
  if (XRAW && f32) {
    const f32x4* xr = (const f32x4*)((const float*)x + (size_t)row * 1024 + L * 16);
#pragma unroll
    for (int i = 0; i < 4; ++i) {
      f32x4 vv = xr[i];
#pragma unroll
      for (int j = 0; j < 4; ++j) xv[i * 4 + j] = vv[j];
    }
  } else {
    const u16* xr = (const u16*)x + (size_t)row * 1024 + L * 16;
    unpack8(*(const u32x4*)xr, xv);
    unpack8(*(const u32x4*)(xr + 8), xv + 8);
  }
  float s = 0.f, sq = 0.f;
#pragma unroll
  for (int i = 0; i < 16; ++i) { s += xv[i]; sq += xv[i] * xv[i]; }
#pragma unroll
  for (int m = 1; m < 64; m <<= 1) { s += __shfl_xor(s, m); sq += __shfl_xor(sq, m); }
  float mean = s * (1.0f / 1024.0f);
  float var = sq * (1.0f / 1024.0f) - mean * mean;
  float rstd = rsqrtf(var + 1e-5f);
  u32 pk[8];
#pragma unroll
  for (int i = 0; i < 8; ++i) {
    float w0 = ldf(w, L * 16 + 2 * i, f32), w1 = ldf(w, L * 16 + 2 * i + 1, f32);
    float b0 = ldf(b, L * 16 + 2 * i, f32), b1v = ldf(b, L * 16 + 2 * i + 1, f32);
    float v0 = (xv[2 * i] - mean) * rstd * w0 + b0;
    float v1 = (xv[2 * i + 1] - mean) * rstd * w1 + b1v;
    pk[i] = (u32)f2bf(v0) | ((u32)f2bf(v1) << 16);
  }
  u32x4 o0 = {pk[0], pk[1], pk[2], pk[3]};
  u32x4 o1 = {pk[4], pk[5], pk[6], pk[7]};
  *(u32x4*)(out + (size_t)row * 1024 + L * 16) = o0;
  *(u32x4*)(out + (size_t)row * 1024 + L * 16 + 8) = o1;
}

// -------- transpose+convert: dst[z][c][r] = (bf16)src_z[r][c], z-multiplexed --------
__global__ __launch_bounds__(256) void twc_kernel(const void* __restrict__ s0,
                                                  const void* __restrict__ s1,
                                                  const void* __restrict__ s2,
                                                  u16* __restrict__ dst, int sstride,
                                                  int dstride, size_t soff, size_t dzoff,
                                                  const int* __restrict__ flag) {
  __shared__ __align__(16) u16 tile[64][72];
  const bool f32 = flag[0] == 0;
  const void* src = blockIdx.z == 0 ? s0 : (blockIdx.z == 1 ? s1 : s2);
  u16* dz = dst + (size_t)blockIdx.z * dzoff;
  const int r0 = blockIdx.y * 64, c0 = blockIdx.x * 64;
  const int t = threadIdx.x;
  const int rr = t >> 3, cc = t & 7;
#pragma unroll
  for (int i = 0; i < 2; ++i) {
    int row = rr + i * 32;
    size_t idx = (size_t)(r0 + row) * sstride + c0 + cc * 8 + soff;
    if (f32) {
      const f32x4* s = (const f32x4*)((const float*)src + idx);
      f32x4 a = s[0], b = s[1];
      union { u16 t16[8]; u32x4 v; } u_;
#pragma unroll
      for (int j = 0; j < 4; ++j) { u_.t16[j] = f2bf(a[j]); u_.t16[4 + j] = f2bf(b[j]); }
      *(u32x4*)(&tile[row][cc * 8]) = u_.v;
    } else {
      *(u32x4*)(&tile[row][cc * 8]) = *(const u32x4*)((const u16*)src + idx);
    }
  }
  __syncthreads();
  u16* d = dz + (size_t)c0 * dstride + r0;
#pragma unroll
  for (int i = 0; i < 2; ++i) {
    int n = rr + i * 32;
    union { u16 t16[8]; u32x4 v; } u_;
#pragma unroll
    for (int j = 0; j < 8; ++j) u_.t16[j] = tile[cc * 8 + j][n];
    *(u32x4*)(d + (size_t)n * dstride + cc * 8) = u_.v;
  }
}

// ------------- GEMM: C(MxN) = A(MxK) * Bt(NxK)^T, tile TM x 128 --------------
// DB=true: double-buffered LDS, ONE barrier per K-step (sync; stage next;
// compute cur). DB=false: classic 2-barrier (for high-occupancy launches).
enum { EP_NONE = 0, EP_RES = 2, EP_GELU = 3, EP_BIASRES = 4, EP_QKV = 5 };

template <int TM, int EPI, bool RESRAW, bool OUTFLEX, bool DB>
__global__ __launch_bounds__(256, 2) void gemm_bt(
    const u16* __restrict__ A, const u16* __restrict__ Bt, void* __restrict__ Cv,
    int M, int N, int K, const void* __restrict__ bias, int boff,
    const void* __restrict__ res, const int* __restrict__ flag,
    u16* __restrict__ kout, u16* __restrict__ vtout) {
  constexpr int MT = TM / 32;         // acc tiles per wave in M
  constexpr int HALF = TM * 64 + 128 * 64;  // u16 per buffer
  extern __shared__ __align__(16) u16 lds[];
  const int t = threadIdx.x;
  const int w = t >> 6, L = t & 63;
  const int quad = L >> 4, l16 = L & 15;
  const int m0 = blockIdx.y * TM, n0 = blockIdx.x * 128;
  const int wm = (TM == 128) ? (w >> 1) * 64 : (w & 1) * 32;
  const int wn = (TM == 128) ? (w & 1) * 64 : (w >> 1) * 64;
  const int srow = L >> 3, spc = L & 7;
  const int sc = spc ^ srow;

  f32x4 acc[MT][4] = {};
  const u16* Ab = A + (size_t)m0 * K;
  const u16* Bb = Bt + (size_t)n0 * K;

  auto stage = [&](int kt, int bsel) {
    u16* base = lds + bsel * HALF;
#pragma unroll
    for (int r = 0; r < TM / 32; ++r) {
      int row = r * 32 + w * 8 + srow;
      async16(Ab + (size_t)row * K + kt + sc * 8, &base[row * 64 + spc * 8]);
    }
#pragma unroll
    for (int r = 0; r < 4; ++r) {
      int row = r * 32 + w * 8 + srow;
      async16(Bb + (size_t)row * K + kt + sc * 8, &base[TM * 64 + row * 64 + spc * 8]);
    }
  };
  auto ktile = [&](const u16* base) {
#pragma unroll
    for (int ks = 0; ks < 2; ++ks) {
      bf16x8 af[MT], bfr[4];
#pragma unroll
      for (int mt = 0; mt < MT; ++mt) {
        int row = wm + mt * 16 + l16;
        af[mt] = ld8(&base[row * 64 + (((ks * 4 + quad) ^ (l16 & 7)) * 8)]);
      }
#pragma unroll
      for (int nt = 0; nt < 4; ++nt) {
        int row = wn + nt * 16 + l16;
        bfr[nt] = ld8(&base[TM * 64 + row * 64 + (((ks * 4 + quad) ^ (l16 & 7)) * 8)]);
      }
#pragma unroll
      for (int mt = 0; mt < MT; ++mt)
#pragma unroll
        for (int nt = 0; nt < 4; ++nt)
          acc[mt][nt] =
              __builtin_amdgcn_mfma_f32_16x16x32_bf16(af[mt], bfr[nt], acc[mt][nt], 0, 0, 0);
    }
  };

  if (DB) {
    const int nst = K >> 6;
    stage(0, 0);
    for (int st = 0; st < nst; ++st) {
      __syncthreads();  // drains own DMA(st); all waves done with buf[(st+1)&1]
      if (st + 1 < nst) stage((st + 1) << 6, (st + 1) & 1);
      ktile(lds + (st & 1) * HALF);
    }
  } else {
    for (int kt = 0; kt < K; kt += 64) {
      stage(kt, 0);
      __syncthreads();
      ktile(lds);
      __syncthreads();
    }
  }

  const bool f32 = flag[0] == 0;
#pragma unroll
  for (int mt = 0; mt < MT; ++mt) {
#pragma unroll
    for (int nt = 0; nt < 4; ++nt) {
      int col = n0 + wn + nt * 16 + l16;
      float bv = 0.f;
      if (EPI == EP_GELU || EPI == EP_BIASRES) bv = ldf(bias, (size_t)boff + col, f32);
#pragma unroll
      for (int r = 0; r < 4; ++r) {
        int row = m0 + wm + mt * 16 + quad * 4 + r;
        float v = acc[mt][nt][r];
        if (EPI == EP_GELU) {
          v += bv;
          v = 0.5f * v * (1.0f + erff(v * 0.70710678118654752f));
        }
        if (EPI == EP_RES || EPI == EP_BIASRES) {
          size_t ri = (size_t)row * N + col;
          float rv = RESRAW ? ldf(res, ri, f32) : bf2f(((const u16*)res)[ri]);
          v += rv;
          if (EPI == EP_BIASRES) v += bv;
        }
        if (EPI == EP_QKV) {
          if (col < 1024) {
            ((u16*)Cv)[(size_t)row * 1024 + col] = f2bf(v * 0.125f);  // q, pre-scaled
          } else if (col < 2048) {
            kout[(size_t)row * 1024 + (col - 1024)] = f2bf(v);  // k
          } else {  // v stored transposed: vT[(b*8+h)*128+d][2048]
            int c2 = col - 2048;
            int bb = row >> 11, n = row & 2047, hh = c2 >> 7, d = c2 & 127;
            vtout[(size_t)((bb * 8 + hh) * 128 + d) * 2048 + n] = f2bf(v);
          }
        } else {
          size_t ci = (size_t)row * N + col;
          if (OUTFLEX && f32)
            ((float*)Cv)[ci] = v;
          else
            ((u16*)Cv)[ci] = f2bf(v);
        }
      }
    }
  }
}

// ---------------- Flash differential attention (K/V dbuf, 1 barrier/tile) ----------
// grid 512 = b(2) x h(8) x qtile(32 of 64 rows), XCD-remapped. 4 waves:
// comp=w>>1, rh=(w&1)*32 (32 q-rows per wave, 2 mt of 16).
// LDS (u16, 80KB dynamic): K[2buf][2comp][64][64] @0 | V[2buf][128][64] @16384
//                        | P/Qstage[4][32][64] @32768
// Per tile: __syncthreads (drains DMA issued a FULL tile ago); stage(ti+1)
// into buf^1; QK+softmax+P(wave-private)+PV from buf. No other sync.
// Defer-max (THR=8); exp2 via fmaf; S^T=mfma(K,Q), O^T=mfma(vT,P^T).
__global__ __launch_bounds__(256, 2) void attn_kernel(
    const u16* __restrict__ q, const u16* __restrict__ k, const u16* __restrict__ vT,
    const float* __restrict__ lamp, const void* __restrict__ subw,
    const int* __restrict__ flag, u16* __restrict__ o) {
  extern __shared__ __align__(16) u16 lds[];
  constexpr int VB = 16384, PB = 32768;
  const int t = threadIdx.x, w = t >> 6, L = t & 63;
  const int quad = L >> 4, l16 = L & 15;
  // bijective XCD remap (512 = 8 x 64): XCD x keeps (b,h) pairs {2x,2x+1}
  const int bid = ((blockIdx.x & 7) << 6) | (blockIdx.x >> 3);
  const int qt = bid & 31, h = (bid >> 5) & 7, b = bid >> 8;
  const int q0 = qt * 64;
  const int comp = w >> 1, rh = (w & 1) * 32;
  const int srow = L >> 3, spc = L & 7, sc = spc ^ srow;
  const u16* vb = vT + (size_t)(b * 8 + h) * (128 * 2048);
  const int pbase = PB + w * 2048;

  auto stageK = [&](int kt, int bsel) {
#pragma unroll
    for (int r = 0; r < 4; ++r) {
      int row = r * 32 + w * 8 + srow;  // comp=row>>6, key=row&63
      int c_ = row >> 6, key = row & 63;
      async16(k + ((size_t)(b * 2048 + kt + key) * 1024 + (2 * h + c_) * 64 + sc * 8),
              &lds[bsel * 8192 + row * 64 + spc * 8]);
    }
  };
  auto stageV = [&](int kt, int bsel) {
#pragma unroll
    for (int r = 0; r < 4; ++r) {
      int dim = r * 32 + w * 8 + srow;  // 0..127
      async16(vb + (size_t)dim * 2048 + kt + sc * 8,
              &lds[VB + bsel * 8192 + dim * 64 + spc * 8]);
    }
  };

  stageK(0, 0);
  stageV(0, 0);
  // stage Q (both comps) into P region
#pragma unroll
  for (int r = 0; r < 4; ++r) {
    int row = r * 32 + w * 8 + srow;  // 0..127 : comp=row>>6, qrow=row&63
    int c_ = row >> 6, qr = row & 63;
    async16(q + ((size_t)(b * 2048 + q0 + qr) * 1024 + (2 * h + c_) * 64 + sc * 8),
            &lds[PB + row * 64 + spc * 8]);
  }
  __syncthreads();  // initial DMA (K0, V0, Q) drained for all waves
  bf16x8 qf[2][2];
#pragma unroll
  for (int mt = 0; mt < 2; ++mt)
#pragma unroll
    for (int ks = 0; ks < 2; ++ks) {
      int row = rh + mt * 16 + l16;
      qf[mt][ks] =
          ld8(&lds[PB + comp * 4096 + row * 64 + (((ks * 4 + quad) ^ (l16 & 7)) * 8)]);
    }
  // no barrier: each wave's qf rows == its own (later) P rows; in-wave DS order

  float mst[2] = {-1.0e30f, -1.0e30f};
  float mstl[2] = {-1.0e30f, -1.0e30f};
  float lst[2] = {0.f, 0.f};
  f32x4 oacc[8][2] = {};

  for (int ti = 0; ti < 32; ++ti) {
    __syncthreads();  // drains own DMA(ti) (issued last iter); all waves done
                      // reading buf^1 (tile ti-1) -> safe to restage it
    const int bb = ti & 1;
    if (ti + 1 < 32) {
      stageK((ti + 1) * 64, bb ^ 1);
      stageV((ti + 1) * 64, bb ^ 1);
    }

    // S^T = Ktile * Q^T for own comp; lane owns qrow = l16 (per mt tile)
    f32x4 s[4][2] = {};
#pragma unroll
    for (int ks = 0; ks < 2; ++ks) {
      bf16x8 kf[4];
#pragma unroll
      for (int nt = 0; nt < 4; ++nt) {
        int row = nt * 16 + l16;
        kf[nt] = ld8(&lds[bb * 8192 + comp * 4096 + row * 64 +
                          (((ks * 4 + quad) ^ (l16 & 7)) * 8)]);
      }
#pragma unroll
      for (int nt = 0; nt < 4; ++nt)
#pragma unroll
        for (int mt = 0; mt < 2; ++mt)
          s[nt][mt] = __builtin_amdgcn_mfma_f32_16x16x32_bf16(kf[nt], qf[mt][ks], s[nt][mt], 0, 0, 0);
    }

    // online softmax with defer-max: per-lane qrow, 2 shfl per reduce
#pragma unroll
    for (int mt = 0; mt < 2; ++mt) {
      float mx = -3.0e38f;
#pragma unroll
      for (int nt = 0; nt < 4; ++nt)
#pragma unroll
        for (int r = 0; r < 4; ++r) mx = fmaxf(mx, s[nt][mt][r]);
      mx = fmaxf(mx, __shfl_xor(mx, 16));
      mx = fmaxf(mx, __shfl_xor(mx, 32));
      if (__ballot(mx > mst[mt] + 8.0f)) {  // wave-uniform
        float mnew = fmaxf(mst[mt], mx);
        float al = exp2f((mst[mt] - mnew) * LOG2E);
        mst[mt] = mnew;
        mstl[mt] = mnew * LOG2E;
        lst[mt] *= al;
#pragma unroll
        for (int nt = 0; nt < 8; ++nt)
#pragma unroll
          for (int r = 0; r < 4; ++r) oacc[nt][mt][r] *= al;
      }
      float ps = 0.f;
#pragma unroll
      for (int nt = 0; nt < 4; ++nt)
#pragma unroll
        for (int r = 0; r < 4; ++r) {
          float p = exp2f(__builtin_fmaf(s[nt][mt][r], LOG2E, -mstl[mt]));
          s[nt][mt][r] = p;
          ps += p;
        }
      ps += __shfl_xor(ps, 16);
      ps += __shfl_xor(ps, 32);
      lst[mt] += ps;
    }

    // P pack -> LDS P[qrow][key] (B-operand readable), wave-private region.
#pragma unroll
    for (int mt = 0; mt < 2; ++mt) {
      int prow = mt * 16 + l16;
#pragma unroll
      for (int nt = 0; nt < 4; ++nt) {
        int pc = (nt * 2 + (quad >> 1)) ^ (l16 & 7);
        u32x2 pk2 = {cvtpk(s[nt][mt][0], s[nt][mt][1]), cvtpk(s[nt][mt][2], s[nt][mt][3])};
        *(u32x2*)(&lds[pbase + prow * 64 + pc * 8 + (quad & 1) * 4]) = pk2;
      }
    }
    // no barrier: P is wave-private; in-wave DS ordering

    // O^T += Vtile^T * P^T
#pragma unroll
    for (int ks = 0; ks < 2; ++ks) {
      bf16x8 pf[2];
#pragma unroll
      for (int mt = 0; mt < 2; ++mt) {
        int row = mt * 16 + l16;
        pf[mt] = ld8(&lds[pbase + row * 64 + (((ks * 4 + quad) ^ (l16 & 7)) * 8)]);
      }
#pragma unroll
      for (int nt = 0; nt < 8; ++nt) {
        int dim = nt * 16 + l16;
        bf16x8 vf = ld8(&lds[VB + bb * 8192 + dim * 64 +
                             (((ks * 4 + quad) ^ (l16 & 7)) * 8)]);
#pragma unroll
        for (int mt = 0; mt < 2; ++mt)
          oacc[nt][mt] = __builtin_amdgcn_mfma_f32_16x16x32_bf16(vf, pf[mt], oacc[nt][mt], 0, 0, 0);
      }
    }
  }

  // normalize by l (per-lane scalar per mt)
#pragma unroll
  for (int mt = 0; mt < 2; ++mt) {
    float inv = 1.0f / lst[mt];
#pragma unroll
    for (int nt = 0; nt < 8; ++nt)
#pragma unroll
      for (int r = 0; r < 4; ++r) oacc[nt][mt][r] *= inv;
  }

  __syncthreads();  // all waves done with K/V/P -> cb may reuse LDS base
  // combine: comp1 waves dump normalized O2^T (f32x4) to LDS; comp0 diff+RMS+store
  float* cb = (float*)lds;  // 64 rows x 132 floats: cb[qrow][dim] (33.8KB < K region)
  if (comp == 1) {
#pragma unroll
    for (int mt = 0; mt < 2; ++mt) {
      int rowc = rh + mt * 16 + l16;
#pragma unroll
      for (int nt = 0; nt < 8; ++nt)
        *(f32x4*)(&cb[rowc * 132 + nt * 16 + quad * 4]) = oacc[nt][mt];
    }
  }
  __syncthreads();
  if (comp == 0) {
    const bool f32 = flag[0] == 0;
    float lam = lamp[0];
    float sw[8][4];
#pragma unroll
    for (int nt = 0; nt < 8; ++nt)
#pragma unroll
      for (int r = 0; r < 4; ++r) sw[nt][r] = ldf(subw, nt * 16 + quad * 4 + r, f32);
#pragma unroll
    for (int mt = 0; mt < 2; ++mt) {
      int rowc = rh + mt * 16 + l16;
      float dv[8][4];
      float sq = 0.f;
#pragma unroll
      for (int nt = 0; nt < 8; ++nt) {
        f32x4 c2 = *(const f32x4*)(&cb[rowc * 132 + nt * 16 + quad * 4]);
#pragma unroll
        for (int r = 0; r < 4; ++r) {
          float d = oacc[nt][mt][r] - lam * c2[r];
          dv[nt][r] = d;
          sq += d * d;
        }
      }
      sq += __shfl_xor(sq, 16);
      sq += __shfl_xor(sq, 32);
      float rms = rsqrtf(sq * (1.0f / 128.0f) + 1e-5f);
      size_t rowg = (size_t)(b * 2048 + q0 + rowc) * 1024 + h * 128;
#pragma unroll
      for (int nt = 0; nt < 8; ++nt) {
        float v0 = dv[nt][0] * rms * sw[nt][0] * ONE_MINUS_LAM_INIT;
        float v1 = dv[nt][1] * rms * sw[nt][1] * ONE_MINUS_LAM_INIT;
        float v2 = dv[nt][2] * rms * sw[nt][2] * ONE_MINUS_LAM_INIT;
        float v3 = dv[nt][3] * rms * sw[nt][3] * ONE_MINUS_LAM_INIT;
        u32x2 pk2 = {cvtpk(v0, v1), cvtpk(v2, v3)};
        *(u32x2*)(o + rowg + nt * 16 + quad * 4) = pk2;
      }
    }
  }
}

// ---------------- host ----------------
extern "C" void kernel_launch(void* const* d_in, const int* in_sizes, int n_in,
                              void* d_out, int out_size, void* d_ws, size_t ws_size,
                              hipStream_t stream) {
  (void)in_sizes; (void)n_in; (void)out_size; (void)ws_size;
  const void* x = d_in[0];
  const void* ln1w = d_in[1];
  const void* ln1b = d_in[2];
  const void* Wq = d_in[3];
  const void* Wk = d_in[4];
  const void* Wv = d_in[5];
  const void* Wo = d_in[6];
  const void* lq1 = d_in[7];
  const void* lk1 = d_in[8];
  const void* lq2 = d_in[9];
  const void* lk2 = d_in[10];
  const void* subw = d_in[11];
  const void* ln2w = d_in[12];
  const void* ln2b = d_in[13];
  const void* W1 = d_in[14];
  const void* b1 = d_in[15];
  const void* W2 = d_in[16];
  const void* b2 = d_in[17];

  char* ws = (char*)d_ws;
  const size_t MB = 1u << 20;
  u16* A = (u16*)ws;               // h1 -> ob -> h2
  u16* B = (u16*)(ws + 8 * MB);    // q -> g (16MB contiguous over B+C)
  u16* C = (u16*)(ws + 16 * MB);   // k -> g(hi)
  u16* D = (u16*)(ws + 24 * MB);   // vT -> WoT -> W1Th|W2Th
  u16* E = (u16*)(ws + 32 * MB);   // WqT|WkT|WvT -> x2
  float* lam = (float*)(ws + 40 * MB);
  int* flag = (int*)(ws + 40 * MB + 64);
  u16* W2Th = D + 2097152;

  // dynamic-LDS sizes (bytes): gemm HALF = (TM*64 + 128*64)*2
  const int g64_1 = (64 * 64 + 128 * 64) * 2;       // 24576, single-buffer
  const int g64_2 = g64_1 * 2;                      // 49152, double-buffer
  const int g128_2 = (128 * 64 + 128 * 64) * 2 * 2; // 65536, double-buffer

  detect_kernel<<<dim3(1), dim3(64), 0, stream>>>((const u32*)x, flag);
  lam_kernel<<<dim3(1), dim3(64), 0, stream>>>(lq1, lk1, lq2, lk2, flag, lam);
  ln_kernel<true><<<dim3(1024), dim3(256), 0, stream>>>(x, ln1w, ln1b, flag, A);

  // Wq|Wk|Wv -> E concatenated n-major (3072 x 1024)
  twc_kernel<<<dim3(16, 16, 3), dim3(256), 0, stream>>>(Wq, Wk, Wv, E, 1024, 1024, 0,
                                                        1048576, flag);
  // fused q/k/v projection: q->B (pre-scaled), k->C, vT->D  (6 blk/CU: no DB)
  gemm_bt<64, EP_QKV, false, false, false><<<dim3(24, 64), dim3(256), g64_1, stream>>>(
      A, E, B, 4096, 3072, 1024, nullptr, 0, nullptr, flag, C, D);

  attn_kernel<<<dim3(512), dim3(256), 81920, stream>>>(B, C, D, lam, subw, flag, A);

  // WoT -> D (vT dead); x2(bf16) = ob @ Wo + x -> E (Wq..WvT dead)
  twc_kernel<<<dim3(16, 16, 1), dim3(256), 0, stream>>>(Wo, Wo, Wo, D, 1024, 1024, 0, 0,
                                                        flag);
  gemm_bt<64, EP_RES, true, false, true><<<dim3(8, 64), dim3(256), g64_2, stream>>>(
      A, D, E, 4096, 1024, 1024, nullptr, 0, x, flag, nullptr, nullptr);
  ln_kernel<false><<<dim3(1024), dim3(256), 0, stream>>>(E, ln2w, ln2b, flag, A);

  // FFN in two FF-column halves; g = B..C (16MB contiguous), full-M launches
  for (int hh = 0; hh < 2; ++hh) {
    twc_kernel<<<dim3(32, 16, 1), dim3(256), 0, stream>>>(W1, W1, W1, D, 4096, 1024,
                                                          (size_t)hh * 2048, 0, flag);
    twc_kernel<<<dim3(16, 32, 1), dim3(256), 0, stream>>>(
        W2, W2, W2, W2Th, 1024, 2048, (size_t)hh * 2048 * 1024, 0, flag);
    gemm_bt<128, EP_GELU, false, false, true><<<dim3(16, 32), dim3(256), g128_2, stream>>>(
        A, D, B, 4096, 2048, 1024, b1, hh * 2048, nullptr, flag, nullptr, nullptr);
    if (hh == 0) {
      gemm_bt<64, EP_BIASRES, false, true, true><<<dim3(8, 64), dim3(256), g64_2, stream>>>(
          B, W2Th, d_out, 4096, 1024, 2048, b2, 0, E, flag, nullptr, nullptr);
    } else {
      gemm_bt<64, EP_RES, true, true, true><<<dim3(8, 64), dim3(256), g64_2, stream>>>(
          B, W2Th, d_out, 4096, 1024, 2048, nullptr, 0, d_out, flag, nullptr, nullptr);
    }
  }
}